// Round 9
// baseline (243.663 us; speedup 1.0000x reference)
//
#include <hip/hip_runtime.h>
#include <stdint.h>

#define BB 8
#define LLEN 16384
#define CC 64
#define TOUT 8186
#define TILE_T 32
#define NPAIR 38            // pair-rows: (2*TILE_T + 12)/2
#define SXPS 68             // u32 per pair-row (272B)
#define SXGS 72             // shorts per gate row (144B)
#define YNS 66              // fp32 words per yn row
#define YNBS 76             // shorts per yn bf16 row

typedef __attribute__((ext_vector_type(8))) short short8;
typedef __attribute__((ext_vector_type(4))) float float4v;
typedef __attribute__((ext_vector_type(4))) unsigned int uint4v;
typedef __attribute__((ext_vector_type(4))) unsigned short ushort4v;

__device__ inline unsigned short f2bf(float f) {
  union { float f; uint32_t u; } v; v.f = f;
  uint32_t r = v.u + 0x7fffu + ((v.u >> 16) & 1u);
  return (unsigned short)(r >> 16);
}
__device__ inline float rcp_fast(float x) {
  float r; asm("v_rcp_f32 %0, %1" : "=v"(r) : "v"(x)); return r;
}
// Pade(5,4) tanh on clamped domain; max |err| ~1.3e-3, validated R8 (absmax unchanged).
__device__ inline float tanh_fast(float a) {
  float t = fminf(fmaxf(a, -3.4f), 3.4f);
  float s = t * t;
  float u = 105.0f + s;
  float v = 945.0f + s * u;
  float w = __builtin_fmaf(s, 15.0f, 420.0f);
  float d = __builtin_fmaf(s, w, 945.0f);
  return (t * v) * rcp_fast(d);
}

// Pack fp32 weights (C,C,K) -> bf16 MFMA B-frags (n = kk*64+d), and
// fp32 conv_kernel (C,C) -> bf16 B-frags (n = o, k = c).
__global__ void prep_frags(const float* __restrict__ weights,
                           const float* __restrict__ ck,
                           unsigned short* __restrict__ wfrag,
                           unsigned short* __restrict__ ckfrag)
{
  int bid = blockIdx.x, tid = threadIdx.x;
  if (bid < 56) {                       // 28 ntiles x 2 khalves
    int nt = bid >> 1, kh = bid & 1;
    for (int e = tid; e < 512; e += 256) {
      int ln = e >> 3, j = e & 7;
      int kk = nt >> 2;                 // nt = kk*4 + dq
      int d  = (nt & 3) * 16 + (ln & 15);
      int cp = kh * 32 + (ln >> 4) * 8 + j;
      wfrag[(bid * 64 + ln) * 8 + j] = f2bf(weights[d * 448 + cp * 7 + kk]);
    }
  } else {                              // conv kernel: 4 ntiles x 2 khalves
    int bb2 = bid - 56;
    int nt = bb2 >> 1, kh = bb2 & 1;
    for (int e = tid; e < 512; e += 256) {
      int ln = e >> 3, j = e & 7;
      int oo = nt * 16 + (ln & 15);
      int c2 = kh * 32 + (ln >> 4) * 8 + j;
      ckfrag[(bb2 * 64 + ln) * 8 + j] = f2bf(ck[c2 * 64 + oo]);
    }
  }
}

__global__ __launch_bounds__(256, 6)
void convblock_main(const float* __restrict__ x,
                    const unsigned short* __restrict__ wfrag,
                    const unsigned short* __restrict__ ckfrag,
                    const float* __restrict__ ln_scale,
                    const float* __restrict__ ln_bias,
                    const float* __restrict__ conv_bias,
                    const float* __restrict__ prelu_slope,
                    float* __restrict__ out)
{
  __shared__ __align__(16) char smem[19552];
  uint32_t*       sxp = (uint32_t*)smem;                 // [0,10336): packed bf16 pairs, swizzled
  unsigned short* ynb = (unsigned short*)smem;           // overlay after B3 (4864 B)
  unsigned short* sxg = (unsigned short*)(smem + 10336); // 9216 B: gate rows bf16
  float*          ynf = (float*)(smem + 10336);          // overlay after B2 (8448 B)

  const int tid  = threadIdx.x;
  const int b    = blockIdx.x >> 8;
  const int t0   = (blockIdx.x & 255) * TILE_T;
  const int lane = tid & 63;
  const int w    = tid >> 6;
  const int l15  = tid & 15;
  const int q    = (tid >> 4) & 3;

  // ---- phase 1: stage x slab rows 2t0..2t0+75 as packed bf16 pairs + gate rows ----
  {
    const float* xb = x + (size_t)b * ((size_t)LLEN * CC);
    #pragma unroll
    for (int i = 0; i < 3; ++i) {
      int u = tid + i * 256;
      if (u < NPAIR * 16) {
        int rp = u >> 4, f4 = u & 15, c0 = f4 * 4;
        int g0 = 2 * t0 + 2 * rp, g1 = g0 + 1;
        if (g0 > LLEN - 1) g0 = LLEN - 1;       // only feeds t >= TOUT (never stored)
        if (g1 > LLEN - 1) g1 = LLEN - 1;
        float4v ve = *(const float4v*)(xb + (size_t)g0 * CC + c0);
        float4v vo = *(const float4v*)(xb + (size_t)g1 * CC + c0);
        ushort4v pe, po;
        #pragma unroll
        for (int j = 0; j < 4; ++j) { pe[j] = f2bf(ve[j]); po[j] = f2bf(vo[j]); }
        int sw = rp & 7;
        #pragma unroll
        for (int j = 0; j < 4; ++j) {
          int c = c0 + j;
          sxp[rp * SXPS + (((c & 15) ^ sw) << 2) + (c >> 4)] =
              (uint32_t)pe[j] | ((uint32_t)po[j] << 16);
        }
        int r0 = 2 * rp, r1 = r0 + 1;
        if (r0 >= 12) *(ushort4v*)&sxg[(r0 - 12) * SXGS + c0] = pe;
        if (r1 >= 12) *(ushort4v*)&sxg[(r1 - 12) * SXGS + c0] = po;
      }
    }
  }
  float lnS[4], lnB[4];
  #pragma unroll
  for (int dq = 0; dq < 4; ++dq) {
    lnS[dq] = ln_scale[16 * dq + l15];
    lnB[dq] = ln_bias[16 * dq + l15];
  }
  __syncthreads();                              // B1

  short8 a0 = *(const short8*)&sxg[(16 * w + l15) * SXGS + q * 8];
  short8 a1 = *(const short8*)&sxg[(16 * w + l15) * SXGS + 32 + q * 8];
  __syncthreads();                              // B2: all sxg reads done (ynf may overlay)

  // ---- phase 2+3 fused: per-kk MFMA -> unpack -> tanh -> y ----
  float y[2][4];
  #pragma unroll
  for (int dlt = 0; dlt < 2; ++dlt)
    #pragma unroll
    for (int dq = 0; dq < 4; ++dq) y[dlt][dq] = 0.f;

  const float4v zacc = (float4v){0.f, 0.f, 0.f, 0.f};
  const int dtbase = 8 * w + 2 * q;             // local t = dtbase + dlt
  #pragma unroll
  for (int kk = 0; kk < 7; ++kk) {
    float4v acc[4];
    #pragma unroll
    for (int dq = 0; dq < 4; ++dq) {
      int nt = kk * 4 + dq;
      short8 b0 = *(const short8*)&wfrag[((nt * 2 + 0) * 64 + lane) * 8];
      short8 b1 = *(const short8*)&wfrag[((nt * 2 + 1) * 64 + lane) * 8];
      float4v a = __builtin_amdgcn_mfma_f32_16x16x32_bf16(a0, b0, zacc, 0, 0, 0);
      a = __builtin_amdgcn_mfma_f32_16x16x32_bf16(a1, b1, a, 0, 0, 0);
      acc[dq] = a;
    }
    #pragma unroll
    for (int dlt = 0; dlt < 2; ++dlt) {
      int rp = dtbase + dlt + kk;               // pair-row (even=x[2t+2kk], odd=+1)
      uint4v pr = *(const uint4v*)&sxp[rp * SXPS + ((l15 ^ (rp & 7)) << 2)];
      #pragma unroll
      for (int dq = 0; dq < 4; ++dq) {
        uint32_t u = pr[dq];
        float xe = __uint_as_float(u << 16);
        float xo = __uint_as_float(u & 0xffff0000u);
        float ge = tanh_fast(acc[dq][2 * dlt + 0]);
        float go = tanh_fast(acc[dq][2 * dlt + 1]);
        y[dlt][dq] += xe * ge + xo * go;
        if (kk == 6) y[dlt][dq] += xe;          // residual x[12+2t] (= kk=6 even row)
      }
    }
  }

  // ---- LayerNorm (registers + 16-lane shuffle) ----
  float ynr[2][4];
  #pragma unroll
  for (int dlt = 0; dlt < 2; ++dlt) {
    float s1 = y[dlt][0] + y[dlt][1] + y[dlt][2] + y[dlt][3];
    float s2 = y[dlt][0]*y[dlt][0] + y[dlt][1]*y[dlt][1]
             + y[dlt][2]*y[dlt][2] + y[dlt][3]*y[dlt][3];
    #pragma unroll
    for (int m = 1; m < 16; m <<= 1) {
      s1 += __shfl_xor(s1, m, 64);
      s2 += __shfl_xor(s2, m, 64);
    }
    float mu   = s1 * (1.0f / 64.0f);
    float var  = s2 * (1.0f / 64.0f) - mu * mu;
    float rstd = rsqrtf(var + 1e-6f);
    int dt = dtbase + dlt;
    #pragma unroll
    for (int dq = 0; dq < 4; ++dq) {
      float yn = (y[dlt][dq] - mu) * rstd * lnS[dq] + lnB[dq];
      ynr[dlt][dq] = yn;
      ynf[dt * YNS + 16 * dq + l15] = yn;       // sxg-overlay region
    }
  }
  __syncthreads();                              // B3: all sxp reads done

  // ---- write ynb bf16 A-frags (sxp overlay) ----
  #pragma unroll
  for (int dlt = 0; dlt < 2; ++dlt)
    #pragma unroll
    for (int dq = 0; dq < 4; ++dq)
      ynb[(dtbase + dlt) * YNBS + 16 * dq + l15] = f2bf(ynr[dlt][dq]);
  __syncthreads();                              // B4

  // ---- phase 4: z = yn@ck + cb via MFMA, PReLU, out = yn + z ----
  const float sl = prelu_slope[0];
  const int   o  = 16 * w + l15;                // wave w owns o-tile w
  const float cb = conv_bias[o];
  short8 bf0 = *(const short8*)&ckfrag[((w * 2 + 0) * 64 + lane) * 8];
  short8 bf1 = *(const short8*)&ckfrag[((w * 2 + 1) * 64 + lane) * 8];
  #pragma unroll
  for (int mt = 0; mt < 2; ++mt) {
    short8 af0 = *(const short8*)&ynb[(mt * 16 + l15) * YNBS + q * 8];
    short8 af1 = *(const short8*)&ynb[(mt * 16 + l15) * YNBS + 32 + q * 8];
    float4v zc = __builtin_amdgcn_mfma_f32_16x16x32_bf16(af0, bf0, zacc, 0, 0, 0);
    zc = __builtin_amdgcn_mfma_f32_16x16x32_bf16(af1, bf1, zc, 0, 0, 0);
    #pragma unroll
    for (int r = 0; r < 4; ++r) {
      int t  = mt * 16 + 4 * q + r;
      int tg = t0 + t;
      if (tg < TOUT) {
        float z = zc[r] + cb;
        z = (z >= 0.f) ? z : sl * z;
        out[((size_t)b * TOUT + tg) * CC + o] = ynf[t * YNS + o] + z;
      }
    }
  }
}

extern "C" void kernel_launch(void* const* d_in, const int* in_sizes, int n_in,
                              void* d_out, int out_size, void* d_ws, size_t ws_size,
                              hipStream_t stream)
{
  const float* x        = (const float*)d_in[0];
  const float* weights  = (const float*)d_in[1];
  const float* ln_scale = (const float*)d_in[2];
  const float* ln_bias  = (const float*)d_in[3];
  const float* ck       = (const float*)d_in[4];
  const float* cb       = (const float*)d_in[5];
  const float* slope    = (const float*)d_in[6];
  unsigned short* wfrag  = (unsigned short*)d_ws;                  // 57344 B
  unsigned short* ckfrag = (unsigned short*)((char*)d_ws + 57344); // 8192 B

  prep_frags<<<64, 256, 0, stream>>>(weights, ck, wfrag, ckfrag);
  convblock_main<<<BB * 256, 256, 0, stream>>>(x, wfrag, ckfrag, ln_scale,
                                               ln_bias, cb, slope, (float*)d_out);
}

// Round 10
// 168.176 us; speedup vs baseline: 1.4489x; 1.4489x over previous
//
#include <hip/hip_runtime.h>
#include <stdint.h>

#define BB 8
#define LLEN 16384
#define CC 64
#define TOUT 8186
#define TILE_T 32
#define NPAIR 38            // pair-rows: (2*TILE_T + 12)/2
#define SXPS 68             // u32 per pair-row (272B)
#define SXGS 72             // shorts per gate row (144B)
#define YNS 66              // fp32 words per yn row
#define YNBS 76             // shorts per yn bf16 row

typedef __attribute__((ext_vector_type(8))) short short8;
typedef __attribute__((ext_vector_type(4))) float float4v;
typedef __attribute__((ext_vector_type(4))) unsigned int uint4v;
typedef __attribute__((ext_vector_type(4))) unsigned short ushort4v;

__device__ inline unsigned short f2bf(float f) {
  union { float f; uint32_t u; } v; v.f = f;
  uint32_t r = v.u + 0x7fffu + ((v.u >> 16) & 1u);
  return (unsigned short)(r >> 16);
}
__device__ inline float rcp_fast(float x) {
  float r; asm("v_rcp_f32 %0, %1" : "=v"(r) : "v"(x)); return r;
}
// Pade(5,4) tanh on clamped domain; max |err| ~1.3e-3, validated R8 (absmax unchanged).
__device__ inline float tanh_fast(float a) {
  float t = fminf(fmaxf(a, -3.4f), 3.4f);
  float s = t * t;
  float u = 105.0f + s;
  float v = 945.0f + s * u;
  float w = __builtin_fmaf(s, 15.0f, 420.0f);
  float d = __builtin_fmaf(s, w, 945.0f);
  return (t * v) * rcp_fast(d);
}

// Pack fp32 weights (C,C,K) -> bf16 MFMA B-frags (n = kk*64+d), and
// fp32 conv_kernel (C,C) -> bf16 B-frags (n = o, k = c).
__global__ void prep_frags(const float* __restrict__ weights,
                           const float* __restrict__ ck,
                           unsigned short* __restrict__ wfrag,
                           unsigned short* __restrict__ ckfrag)
{
  int bid = blockIdx.x, tid = threadIdx.x;
  if (bid < 56) {                       // 28 ntiles x 2 khalves
    int nt = bid >> 1, kh = bid & 1;
    for (int e = tid; e < 512; e += 256) {
      int ln = e >> 3, j = e & 7;
      int kk = nt >> 2;                 // nt = kk*4 + dq
      int d  = (nt & 3) * 16 + (ln & 15);
      int cp = kh * 32 + (ln >> 4) * 8 + j;
      wfrag[(bid * 64 + ln) * 8 + j] = f2bf(weights[d * 448 + cp * 7 + kk]);
    }
  } else {                              // conv kernel: 4 ntiles x 2 khalves
    int bb2 = bid - 56;
    int nt = bb2 >> 1, kh = bb2 & 1;
    for (int e = tid; e < 512; e += 256) {
      int ln = e >> 3, j = e & 7;
      int oo = nt * 16 + (ln & 15);
      int c2 = kh * 32 + (ln >> 4) * 8 + j;
      ckfrag[(bb2 * 64 + ln) * 8 + j] = f2bf(ck[c2 * 64 + oo]);
    }
  }
}

// launch_bounds (256,4): R9's (256,6) forced VGPR<=85 -> 340MB scratch spill
// (WRITE_SIZE 358MB). 64-VGPR build under (256,4) is spill-free (R8) and
// still allows 8 waves/SIMD; LDS 19.6KB no longer caps residency.
__global__ __launch_bounds__(256, 4)
void convblock_main(const float* __restrict__ x,
                    const unsigned short* __restrict__ wfrag,
                    const unsigned short* __restrict__ ckfrag,
                    const float* __restrict__ ln_scale,
                    const float* __restrict__ ln_bias,
                    const float* __restrict__ conv_bias,
                    const float* __restrict__ prelu_slope,
                    float* __restrict__ out)
{
  __shared__ __align__(16) char smem[19552];
  uint32_t*       sxp = (uint32_t*)smem;                 // [0,10336): packed bf16 pairs, swizzled
  unsigned short* ynb = (unsigned short*)smem;           // overlay after B3 (4864 B)
  unsigned short* sxg = (unsigned short*)(smem + 10336); // 9216 B: gate rows bf16
  float*          ynf = (float*)(smem + 10336);          // overlay after B2 (8448 B)

  const int tid  = threadIdx.x;
  const int b    = blockIdx.x >> 8;
  const int t0   = (blockIdx.x & 255) * TILE_T;
  const int lane = tid & 63;
  const int w    = tid >> 6;
  const int l15  = tid & 15;
  const int q    = (tid >> 4) & 3;

  // ---- phase 1: stage x slab rows 2t0..2t0+75 as packed bf16 pairs + gate rows ----
  {
    const float* xb = x + (size_t)b * ((size_t)LLEN * CC);
    #pragma unroll
    for (int i = 0; i < 3; ++i) {
      int u = tid + i * 256;
      if (u < NPAIR * 16) {
        int rp = u >> 4, f4 = u & 15, c0 = f4 * 4;
        int g0 = 2 * t0 + 2 * rp, g1 = g0 + 1;
        if (g0 > LLEN - 1) g0 = LLEN - 1;       // only feeds t >= TOUT (never stored)
        if (g1 > LLEN - 1) g1 = LLEN - 1;
        float4v ve = *(const float4v*)(xb + (size_t)g0 * CC + c0);
        float4v vo = *(const float4v*)(xb + (size_t)g1 * CC + c0);
        ushort4v pe, po;
        #pragma unroll
        for (int j = 0; j < 4; ++j) { pe[j] = f2bf(ve[j]); po[j] = f2bf(vo[j]); }
        int sw = rp & 7;
        #pragma unroll
        for (int j = 0; j < 4; ++j) {
          int c = c0 + j;
          sxp[rp * SXPS + (((c & 15) ^ sw) << 2) + (c >> 4)] =
              (uint32_t)pe[j] | ((uint32_t)po[j] << 16);
        }
        int r0 = 2 * rp, r1 = r0 + 1;
        if (r0 >= 12) *(ushort4v*)&sxg[(r0 - 12) * SXGS + c0] = pe;
        if (r1 >= 12) *(ushort4v*)&sxg[(r1 - 12) * SXGS + c0] = po;
      }
    }
  }
  float lnS[4], lnB[4];
  #pragma unroll
  for (int dq = 0; dq < 4; ++dq) {
    lnS[dq] = ln_scale[16 * dq + l15];
    lnB[dq] = ln_bias[16 * dq + l15];
  }
  __syncthreads();                              // B1

  short8 a0 = *(const short8*)&sxg[(16 * w + l15) * SXGS + q * 8];
  short8 a1 = *(const short8*)&sxg[(16 * w + l15) * SXGS + 32 + q * 8];
  __syncthreads();                              // B2: all sxg reads done (ynf may overlay)

  // ---- phase 2+3 fused: per-kk MFMA -> unpack -> tanh -> y ----
  float y[2][4];
  #pragma unroll
  for (int dlt = 0; dlt < 2; ++dlt)
    #pragma unroll
    for (int dq = 0; dq < 4; ++dq) y[dlt][dq] = 0.f;

  const float4v zacc = (float4v){0.f, 0.f, 0.f, 0.f};
  const int dtbase = 8 * w + 2 * q;             // local t = dtbase + dlt
  #pragma unroll
  for (int kk = 0; kk < 7; ++kk) {
    float4v acc[4];
    #pragma unroll
    for (int dq = 0; dq < 4; ++dq) {
      int nt = kk * 4 + dq;
      short8 b0 = *(const short8*)&wfrag[((nt * 2 + 0) * 64 + lane) * 8];
      short8 b1 = *(const short8*)&wfrag[((nt * 2 + 1) * 64 + lane) * 8];
      float4v a = __builtin_amdgcn_mfma_f32_16x16x32_bf16(a0, b0, zacc, 0, 0, 0);
      a = __builtin_amdgcn_mfma_f32_16x16x32_bf16(a1, b1, a, 0, 0, 0);
      acc[dq] = a;
    }
    #pragma unroll
    for (int dlt = 0; dlt < 2; ++dlt) {
      int rp = dtbase + dlt + kk;               // pair-row (even=x[2t+2kk], odd=+1)
      uint4v pr = *(const uint4v*)&sxp[rp * SXPS + ((l15 ^ (rp & 7)) << 2)];
      #pragma unroll
      for (int dq = 0; dq < 4; ++dq) {
        uint32_t u = pr[dq];
        float xe = __uint_as_float(u << 16);
        float xo = __uint_as_float(u & 0xffff0000u);
        float ge = tanh_fast(acc[dq][2 * dlt + 0]);
        float go = tanh_fast(acc[dq][2 * dlt + 1]);
        y[dlt][dq] += xe * ge + xo * go;
        if (kk == 6) y[dlt][dq] += xe;          // residual x[12+2t] (= kk=6 even row)
      }
    }
  }

  // ---- LayerNorm (registers + 16-lane shuffle) ----
  float ynr[2][4];
  #pragma unroll
  for (int dlt = 0; dlt < 2; ++dlt) {
    float s1 = y[dlt][0] + y[dlt][1] + y[dlt][2] + y[dlt][3];
    float s2 = y[dlt][0]*y[dlt][0] + y[dlt][1]*y[dlt][1]
             + y[dlt][2]*y[dlt][2] + y[dlt][3]*y[dlt][3];
    #pragma unroll
    for (int m = 1; m < 16; m <<= 1) {
      s1 += __shfl_xor(s1, m, 64);
      s2 += __shfl_xor(s2, m, 64);
    }
    float mu   = s1 * (1.0f / 64.0f);
    float var  = s2 * (1.0f / 64.0f) - mu * mu;
    float rstd = rsqrtf(var + 1e-6f);
    int dt = dtbase + dlt;
    #pragma unroll
    for (int dq = 0; dq < 4; ++dq) {
      float yn = (y[dlt][dq] - mu) * rstd * lnS[dq] + lnB[dq];
      ynr[dlt][dq] = yn;
      ynf[dt * YNS + 16 * dq + l15] = yn;       // sxg-overlay region
    }
  }
  __syncthreads();                              // B3: all sxp reads done

  // ---- write ynb bf16 A-frags (sxp overlay) ----
  #pragma unroll
  for (int dlt = 0; dlt < 2; ++dlt)
    #pragma unroll
    for (int dq = 0; dq < 4; ++dq)
      ynb[(dtbase + dlt) * YNBS + 16 * dq + l15] = f2bf(ynr[dlt][dq]);
  __syncthreads();                              // B4

  // ---- phase 4: z = yn@ck + cb via MFMA, PReLU, out = yn + z ----
  const float sl = prelu_slope[0];
  const int   o  = 16 * w + l15;                // wave w owns o-tile w
  const float cb = conv_bias[o];
  short8 bf0 = *(const short8*)&ckfrag[((w * 2 + 0) * 64 + lane) * 8];
  short8 bf1 = *(const short8*)&ckfrag[((w * 2 + 1) * 64 + lane) * 8];
  #pragma unroll
  for (int mt = 0; mt < 2; ++mt) {
    short8 af0 = *(const short8*)&ynb[(mt * 16 + l15) * YNBS + q * 8];
    short8 af1 = *(const short8*)&ynb[(mt * 16 + l15) * YNBS + 32 + q * 8];
    float4v zc = __builtin_amdgcn_mfma_f32_16x16x32_bf16(af0, bf0, zacc, 0, 0, 0);
    zc = __builtin_amdgcn_mfma_f32_16x16x32_bf16(af1, bf1, zc, 0, 0, 0);
    #pragma unroll
    for (int r = 0; r < 4; ++r) {
      int t  = mt * 16 + 4 * q + r;
      int tg = t0 + t;
      if (tg < TOUT) {
        float z = zc[r] + cb;
        z = (z >= 0.f) ? z : sl * z;
        out[((size_t)b * TOUT + tg) * CC + o] = ynf[t * YNS + o] + z;
      }
    }
  }
}

extern "C" void kernel_launch(void* const* d_in, const int* in_sizes, int n_in,
                              void* d_out, int out_size, void* d_ws, size_t ws_size,
                              hipStream_t stream)
{
  const float* x        = (const float*)d_in[0];
  const float* weights  = (const float*)d_in[1];
  const float* ln_scale = (const float*)d_in[2];
  const float* ln_bias  = (const float*)d_in[3];
  const float* ck       = (const float*)d_in[4];
  const float* cb       = (const float*)d_in[5];
  const float* slope    = (const float*)d_in[6];
  unsigned short* wfrag  = (unsigned short*)d_ws;                  // 57344 B
  unsigned short* ckfrag = (unsigned short*)((char*)d_ws + 57344); // 8192 B

  prep_frags<<<64, 256, 0, stream>>>(weights, ck, wfrag, ckfrag);
  convblock_main<<<BB * 256, 256, 0, stream>>>(x, wfrag, ckfrag, ln_scale,
                                               ln_bias, cb, slope, (float*)d_out);
}

// Round 11
// 112.153 us; speedup vs baseline: 2.1726x; 1.4995x over previous
//
#include <hip/hip_runtime.h>
#include <stdint.h>

#define BB 8
#define LLEN 16384
#define CC 64
#define TOUT 8186
#define TILE_T 32
#define NROWS 76            // 2*TILE_T + 12 halo rows
#define SXS 68              // fp32 words/row (272B)
#define SXGS 72             // shorts/row (144B)
#define YNS 66              // fp32 words/row
#define YNBS 76             // shorts/row

typedef __attribute__((ext_vector_type(8))) short short8;
typedef __attribute__((ext_vector_type(4))) float float4v;
typedef __attribute__((ext_vector_type(4))) unsigned short ushort4v;

__device__ inline unsigned short f2bf(float f) {
  union { float f; uint32_t u; } v; v.f = f;
  uint32_t r = v.u + 0x7fffu + ((v.u >> 16) & 1u);
  return (unsigned short)(r >> 16);
}
__device__ inline float rcp_fast(float x) {
  float r; asm("v_rcp_f32 %0, %1" : "=v"(r) : "v"(x)); return r;
}
// Pade(5,4) tanh on clamped domain; max |err| ~1.3e-3, validated R8 (absmax unchanged).
__device__ inline float tanh_fast(float a) {
  float t = fminf(fmaxf(a, -3.4f), 3.4f);
  float s = t * t;
  float u = 105.0f + s;
  float v = 945.0f + s * u;
  float w = __builtin_fmaf(s, 15.0f, 420.0f);
  float d = __builtin_fmaf(s, w, 945.0f);
  return (t * v) * rcp_fast(d);
}

// Pack fp32 weights (C,C,K) -> bf16 MFMA B-frags (n = kk*64+d), and
// fp32 conv_kernel (C,C) -> bf16 B-frags (n = o, k = c).
__global__ void prep_frags(const float* __restrict__ weights,
                           const float* __restrict__ ck,
                           unsigned short* __restrict__ wfrag,
                           unsigned short* __restrict__ ckfrag)
{
  int bid = blockIdx.x, tid = threadIdx.x;
  if (bid < 56) {                       // 28 ntiles x 2 khalves
    int nt = bid >> 1, kh = bid & 1;
    for (int e = tid; e < 512; e += 256) {
      int ln = e >> 3, j = e & 7;
      int kk = nt >> 2;                 // nt = kk*4 + dq
      int d  = (nt & 3) * 16 + (ln & 15);
      int cp = kh * 32 + (ln >> 4) * 8 + j;
      wfrag[(bid * 64 + ln) * 8 + j] = f2bf(weights[d * 448 + cp * 7 + kk]);
    }
  } else {                              // conv kernel: 4 ntiles x 2 khalves
    int bb2 = bid - 56;
    int nt = bb2 >> 1, kh = bb2 & 1;
    for (int e = tid; e < 512; e += 256) {
      int ln = e >> 3, j = e & 7;
      int oo = nt * 16 + (ln & 15);
      int c2 = kh * 32 + (ln >> 4) * 8 + j;
      ckfrag[(bb2 * 64 + ln) * 8 + j] = f2bf(ck[c2 * 64 + oo]);
    }
  }
}

// R8 body (clean: VGPR 64, no spill, 44.8us) with the kk-loop ROLLED
// (#pragma unroll 1): ~1.5KB loop body instead of ~12KB straight-line.
__global__ __launch_bounds__(256, 4)
void convblock_main(const float* __restrict__ x,
                    const unsigned short* __restrict__ wfrag,
                    const unsigned short* __restrict__ ckfrag,
                    const float* __restrict__ ln_scale,
                    const float* __restrict__ ln_bias,
                    const float* __restrict__ conv_bias,
                    const float* __restrict__ prelu_slope,
                    float* __restrict__ out)
{
  __shared__ __align__(16) char smem[29888];
  float*          sx2 = (float*)smem;                    // [0, 20672)
  unsigned short* ynb = (unsigned short*)smem;           // overlay after B3 (4864 B)
  unsigned short* sxg = (unsigned short*)(smem + 20672); // 9216 B
  float*          ynf = (float*)(smem + 20672);          // overlay after B2 (8448 B)

  const int tid  = threadIdx.x;
  const int b    = blockIdx.x >> 8;
  const int t0   = (blockIdx.x & 255) * TILE_T;
  const int lane = tid & 63;
  const int w    = tid >> 6;
  const int l15  = tid & 15;
  const int q    = (tid >> 4) & 3;

  // ---- phase 1: stage x slab rows 2t0..2t0+75, float4 loads ----
  {
    const float* xb = x + (size_t)b * ((size_t)LLEN * CC);
    #pragma unroll
    for (int i = 0; i < 5; ++i) {
      int idx = tid + i * 256;                  // [0, 1216) float4s
      if (idx < NROWS * 16) {
        int row = idx >> 4, f4 = idx & 15, c0 = f4 * 4;
        int rowg = 2 * t0 + row;
        if (rowg > LLEN - 1) rowg = LLEN - 1;   // only feeds t >= TOUT (never stored)
        float4v v = *(const float4v*)(xb + (size_t)rowg * CC + c0);
        int base = row * SXS + 16 * (f4 & 3) + (f4 >> 2);  // swizzle (c&15)*4+(c>>4)
        sx2[base + 0]  = v[0];
        sx2[base + 4]  = v[1];
        sx2[base + 8]  = v[2];
        sx2[base + 12] = v[3];
        if (row >= 12) {
          ushort4v p;
          p[0] = f2bf(v[0]); p[1] = f2bf(v[1]); p[2] = f2bf(v[2]); p[3] = f2bf(v[3]);
          *(ushort4v*)&sxg[(row - 12) * SXGS + c0] = p;
        }
      }
    }
  }
  float lnS[4], lnB[4];
  #pragma unroll
  for (int dq = 0; dq < 4; ++dq) {
    lnS[dq] = ln_scale[16 * dq + l15];
    lnB[dq] = ln_bias[16 * dq + l15];
  }
  __syncthreads();                              // B1

  short8 a0 = *(const short8*)&sxg[(16 * w + l15) * SXGS + q * 8];
  short8 a1 = *(const short8*)&sxg[(16 * w + l15) * SXGS + 32 + q * 8];
  __syncthreads();                              // B2: sxg dead, ynf may overlay

  // ---- phase 2+3 fused: ROLLED per-kk loop: MFMA -> tanh -> y ----
  float y[2][4];
  #pragma unroll
  for (int dlt = 0; dlt < 2; ++dlt)
    #pragma unroll
    for (int dq = 0; dq < 4; ++dq) y[dlt][dq] = 0.f;

  const float4v zacc = (float4v){0.f, 0.f, 0.f, 0.f};
  const int dtbase = 8 * w + 2 * q;             // local t = dtbase + dlt
  const unsigned short* wp = wfrag + lane * 8;  // += 4096 shorts per kk
  #pragma unroll 1
  for (int kk = 0; kk < 7; ++kk) {
    float4v acc[4];
    #pragma unroll
    for (int dq = 0; dq < 4; ++dq) {
      short8 b0 = *(const short8*)(wp + dq * 1024);
      short8 b1 = *(const short8*)(wp + dq * 1024 + 512);
      float4v a = __builtin_amdgcn_mfma_f32_16x16x32_bf16(a0, b0, zacc, 0, 0, 0);
      acc[dq] = __builtin_amdgcn_mfma_f32_16x16x32_bf16(a1, b1, a, 0, 0, 0);
    }
    #pragma unroll
    for (int dlt = 0; dlt < 2; ++dlt) {
      int rowe = 2 * (dtbase + dlt) + 2 * kk;
      float4v xe = *(const float4v*)&sx2[rowe * SXS + l15 * 4];
      float4v xo = *(const float4v*)&sx2[(rowe + 1) * SXS + l15 * 4];
      #pragma unroll
      for (int dq = 0; dq < 4; ++dq) {
        float ge = tanh_fast(acc[dq][2 * dlt + 0]);
        float go = tanh_fast(acc[dq][2 * dlt + 1]);
        y[dlt][dq] += xe[dq] * ge + xo[dq] * go;
      }
    }
    wp += 4096;
  }
  // residual x[12+2t] (even element of the kk=6 row)
  #pragma unroll
  for (int dlt = 0; dlt < 2; ++dlt) {
    int rowe = 2 * (dtbase + dlt) + 12;
    float4v xe = *(const float4v*)&sx2[rowe * SXS + l15 * 4];
    #pragma unroll
    for (int dq = 0; dq < 4; ++dq) y[dlt][dq] += xe[dq];
  }

  // ---- LayerNorm (registers + 16-lane shuffle) ----
  float ynr[2][4];
  #pragma unroll
  for (int dlt = 0; dlt < 2; ++dlt) {
    float s1 = y[dlt][0] + y[dlt][1] + y[dlt][2] + y[dlt][3];
    float s2 = y[dlt][0]*y[dlt][0] + y[dlt][1]*y[dlt][1]
             + y[dlt][2]*y[dlt][2] + y[dlt][3]*y[dlt][3];
    #pragma unroll
    for (int m = 1; m < 16; m <<= 1) {
      s1 += __shfl_xor(s1, m, 64);
      s2 += __shfl_xor(s2, m, 64);
    }
    float mu   = s1 * (1.0f / 64.0f);
    float var  = s2 * (1.0f / 64.0f) - mu * mu;
    float rstd = rsqrtf(var + 1e-6f);
    int dt = dtbase + dlt;
    #pragma unroll
    for (int dq = 0; dq < 4; ++dq) {
      float yn = (y[dlt][dq] - mu) * rstd * lnS[dq] + lnB[dq];
      ynr[dlt][dq] = yn;
      ynf[dt * YNS + 16 * dq + l15] = yn;       // sxg-overlay region
    }
  }
  __syncthreads();                              // B3: sx2 reads done

  // ---- write ynb bf16 A-frags (sx2 overlay) ----
  #pragma unroll
  for (int dlt = 0; dlt < 2; ++dlt)
    #pragma unroll
    for (int dq = 0; dq < 4; ++dq)
      ynb[(dtbase + dlt) * YNBS + 16 * dq + l15] = f2bf(ynr[dlt][dq]);
  __syncthreads();                              // B4

  // ---- phase 4: z = yn@ck + cb via MFMA, PReLU, out = yn + z ----
  const float sl = prelu_slope[0];
  const int   o  = 16 * w + l15;                // wave w owns o-tile w
  const float cb = conv_bias[o];
  short8 bf0 = *(const short8*)&ckfrag[((w * 2 + 0) * 64 + lane) * 8];
  short8 bf1 = *(const short8*)&ckfrag[((w * 2 + 1) * 64 + lane) * 8];
  #pragma unroll
  for (int mt = 0; mt < 2; ++mt) {
    short8 af0 = *(const short8*)&ynb[(mt * 16 + l15) * YNBS + q * 8];
    short8 af1 = *(const short8*)&ynb[(mt * 16 + l15) * YNBS + 32 + q * 8];
    float4v zc = __builtin_amdgcn_mfma_f32_16x16x32_bf16(af0, bf0, zacc, 0, 0, 0);
    zc = __builtin_amdgcn_mfma_f32_16x16x32_bf16(af1, bf1, zc, 0, 0, 0);
    #pragma unroll
    for (int r = 0; r < 4; ++r) {
      int t  = mt * 16 + 4 * q + r;
      int tg = t0 + t;
      if (tg < TOUT) {
        float z = zc[r] + cb;
        z = (z >= 0.f) ? z : sl * z;
        out[((size_t)b * TOUT + tg) * CC + o] = ynf[t * YNS + o] + z;
      }
    }
  }
}

extern "C" void kernel_launch(void* const* d_in, const int* in_sizes, int n_in,
                              void* d_out, int out_size, void* d_ws, size_t ws_size,
                              hipStream_t stream)
{
  const float* x        = (const float*)d_in[0];
  const float* weights  = (const float*)d_in[1];
  const float* ln_scale = (const float*)d_in[2];
  const float* ln_bias  = (const float*)d_in[3];
  const float* ck       = (const float*)d_in[4];
  const float* cb       = (const float*)d_in[5];
  const float* slope    = (const float*)d_in[6];
  unsigned short* wfrag  = (unsigned short*)d_ws;                  // 57344 B
  unsigned short* ckfrag = (unsigned short*)((char*)d_ws + 57344); // 8192 B

  prep_frags<<<64, 256, 0, stream>>>(weights, ck, wfrag, ckfrag);
  convblock_main<<<BB * 256, 256, 0, stream>>>(x, wfrag, ckfrag, ln_scale,
                                               ln_bias, cb, slope, (float*)d_out);
}

// Round 12
// 110.981 us; speedup vs baseline: 2.1955x; 1.0106x over previous
//
#include <hip/hip_runtime.h>
#include <stdint.h>

#define BB 8
#define LLEN 16384
#define CC 64
#define TOUT 8186
#define TILE_T 32
#define NROWS 76            // 2*TILE_T + 12 halo rows
#define SXS 68              // fp32 words/row (272B)
#define SXGS 72             // shorts/row (144B)
#define YNS 66              // fp32 words/row
#define YNBS 76             // shorts/row

typedef __attribute__((ext_vector_type(8))) short short8;
typedef __attribute__((ext_vector_type(4))) float float4v;
typedef __attribute__((ext_vector_type(4))) unsigned short ushort4v;

__device__ inline unsigned short f2bf(float f) {
  union { float f; uint32_t u; } v; v.f = f;
  uint32_t r = v.u + 0x7fffu + ((v.u >> 16) & 1u);
  return (unsigned short)(r >> 16);
}
__device__ inline float rcp_fast(float x) {
  float r; asm("v_rcp_f32 %0, %1" : "=v"(r) : "v"(x)); return r;
}
__device__ inline float exp2_fast(float x) {
  float r; asm("v_exp_f32 %0, %1" : "=v"(r) : "v"(x)); return r;
}
// exp-form tanh (R6-validated, absmax 0.03125): 5 inst/gate
// (mul, v_exp, add, v_rcp, fma); saturates exactly at +/-1.
__device__ inline float tanh_fast(float a) {
  float e = exp2_fast(a * 2.885390082f);        // e^{2a} = 2^{a*2*log2(e)}
  return __builtin_fmaf(-2.0f, rcp_fast(e + 1.0f), 1.0f);
}

// Pack fp32 weights (C,C,K) -> bf16 MFMA B-frags (n = kk*64+d), and
// fp32 conv_kernel (C,C) -> bf16 B-frags (n = o, k = c).
__global__ void prep_frags(const float* __restrict__ weights,
                           const float* __restrict__ ck,
                           unsigned short* __restrict__ wfrag,
                           unsigned short* __restrict__ ckfrag)
{
  int bid = blockIdx.x, tid = threadIdx.x;
  if (bid < 56) {                       // 28 ntiles x 2 khalves
    int nt = bid >> 1, kh = bid & 1;
    for (int e = tid; e < 512; e += 256) {
      int ln = e >> 3, j = e & 7;
      int kk = nt >> 2;                 // nt = kk*4 + dq
      int d  = (nt & 3) * 16 + (ln & 15);
      int cp = kh * 32 + (ln >> 4) * 8 + j;
      wfrag[(bid * 64 + ln) * 8 + j] = f2bf(weights[d * 448 + cp * 7 + kk]);
    }
  } else {                              // conv kernel: 4 ntiles x 2 khalves
    int bb2 = bid - 56;
    int nt = bb2 >> 1, kh = bb2 & 1;
    for (int e = tid; e < 512; e += 256) {
      int ln = e >> 3, j = e & 7;
      int oo = nt * 16 + (ln & 15);
      int c2 = kh * 32 + (ln >> 4) * 8 + j;
      ckfrag[(bb2 * 64 + ln) * 8 + j] = f2bf(ck[c2 * 64 + oo]);
    }
  }
}

// R11 base (rolled kk-loop, VGPR~64, no spill) + exp-form tanh.
__global__ __launch_bounds__(256, 4)
void convblock_main(const float* __restrict__ x,
                    const unsigned short* __restrict__ wfrag,
                    const unsigned short* __restrict__ ckfrag,
                    const float* __restrict__ ln_scale,
                    const float* __restrict__ ln_bias,
                    const float* __restrict__ conv_bias,
                    const float* __restrict__ prelu_slope,
                    float* __restrict__ out)
{
  __shared__ __align__(16) char smem[29888];
  float*          sx2 = (float*)smem;                    // [0, 20672)
  unsigned short* ynb = (unsigned short*)smem;           // overlay after B3 (4864 B)
  unsigned short* sxg = (unsigned short*)(smem + 20672); // 9216 B
  float*          ynf = (float*)(smem + 20672);          // overlay after B2 (8448 B)

  const int tid  = threadIdx.x;
  const int b    = blockIdx.x >> 8;
  const int t0   = (blockIdx.x & 255) * TILE_T;
  const int lane = tid & 63;
  const int w    = tid >> 6;
  const int l15  = tid & 15;
  const int q    = (tid >> 4) & 3;

  // ---- phase 1: stage x slab rows 2t0..2t0+75, float4 loads ----
  {
    const float* xb = x + (size_t)b * ((size_t)LLEN * CC);
    #pragma unroll
    for (int i = 0; i < 5; ++i) {
      int idx = tid + i * 256;                  // [0, 1216) float4s
      if (idx < NROWS * 16) {
        int row = idx >> 4, f4 = idx & 15, c0 = f4 * 4;
        int rowg = 2 * t0 + row;
        if (rowg > LLEN - 1) rowg = LLEN - 1;   // only feeds t >= TOUT (never stored)
        float4v v = *(const float4v*)(xb + (size_t)rowg * CC + c0);
        int base = row * SXS + 16 * (f4 & 3) + (f4 >> 2);  // swizzle (c&15)*4+(c>>4)
        sx2[base + 0]  = v[0];
        sx2[base + 4]  = v[1];
        sx2[base + 8]  = v[2];
        sx2[base + 12] = v[3];
        if (row >= 12) {
          ushort4v p;
          p[0] = f2bf(v[0]); p[1] = f2bf(v[1]); p[2] = f2bf(v[2]); p[3] = f2bf(v[3]);
          *(ushort4v*)&sxg[(row - 12) * SXGS + c0] = p;
        }
      }
    }
  }
  float lnS[4], lnB[4];
  #pragma unroll
  for (int dq = 0; dq < 4; ++dq) {
    lnS[dq] = ln_scale[16 * dq + l15];
    lnB[dq] = ln_bias[16 * dq + l15];
  }
  __syncthreads();                              // B1

  short8 a0 = *(const short8*)&sxg[(16 * w + l15) * SXGS + q * 8];
  short8 a1 = *(const short8*)&sxg[(16 * w + l15) * SXGS + 32 + q * 8];
  __syncthreads();                              // B2: sxg dead, ynf may overlay

  // ---- phase 2+3 fused: ROLLED per-kk loop: MFMA -> tanh -> y ----
  float y[2][4];
  #pragma unroll
  for (int dlt = 0; dlt < 2; ++dlt)
    #pragma unroll
    for (int dq = 0; dq < 4; ++dq) y[dlt][dq] = 0.f;

  const float4v zacc = (float4v){0.f, 0.f, 0.f, 0.f};
  const int dtbase = 8 * w + 2 * q;             // local t = dtbase + dlt
  const unsigned short* wp = wfrag + lane * 8;  // += 4096 shorts per kk
  #pragma unroll 1
  for (int kk = 0; kk < 7; ++kk) {
    float4v acc[4];
    #pragma unroll
    for (int dq = 0; dq < 4; ++dq) {
      short8 b0 = *(const short8*)(wp + dq * 1024);
      short8 b1 = *(const short8*)(wp + dq * 1024 + 512);
      float4v a = __builtin_amdgcn_mfma_f32_16x16x32_bf16(a0, b0, zacc, 0, 0, 0);
      acc[dq] = __builtin_amdgcn_mfma_f32_16x16x32_bf16(a1, b1, a, 0, 0, 0);
    }
    #pragma unroll
    for (int dlt = 0; dlt < 2; ++dlt) {
      int rowe = 2 * (dtbase + dlt) + 2 * kk;
      float4v xe = *(const float4v*)&sx2[rowe * SXS + l15 * 4];
      float4v xo = *(const float4v*)&sx2[(rowe + 1) * SXS + l15 * 4];
      #pragma unroll
      for (int dq = 0; dq < 4; ++dq) {
        float ge = tanh_fast(acc[dq][2 * dlt + 0]);
        float go = tanh_fast(acc[dq][2 * dlt + 1]);
        y[dlt][dq] += xe[dq] * ge + xo[dq] * go;
      }
    }
    wp += 4096;
  }
  // residual x[12+2t] (even element of the kk=6 row)
  #pragma unroll
  for (int dlt = 0; dlt < 2; ++dlt) {
    int rowe = 2 * (dtbase + dlt) + 12;
    float4v xe = *(const float4v*)&sx2[rowe * SXS + l15 * 4];
    #pragma unroll
    for (int dq = 0; dq < 4; ++dq) y[dlt][dq] += xe[dq];
  }

  // ---- LayerNorm (registers + 16-lane shuffle) ----
  float ynr[2][4];
  #pragma unroll
  for (int dlt = 0; dlt < 2; ++dlt) {
    float s1 = y[dlt][0] + y[dlt][1] + y[dlt][2] + y[dlt][3];
    float s2 = y[dlt][0]*y[dlt][0] + y[dlt][1]*y[dlt][1]
             + y[dlt][2]*y[dlt][2] + y[dlt][3]*y[dlt][3];
    #pragma unroll
    for (int m = 1; m < 16; m <<= 1) {
      s1 += __shfl_xor(s1, m, 64);
      s2 += __shfl_xor(s2, m, 64);
    }
    float mu   = s1 * (1.0f / 64.0f);
    float var  = s2 * (1.0f / 64.0f) - mu * mu;
    float rstd = rsqrtf(var + 1e-6f);
    int dt = dtbase + dlt;
    #pragma unroll
    for (int dq = 0; dq < 4; ++dq) {
      float yn = (y[dlt][dq] - mu) * rstd * lnS[dq] + lnB[dq];
      ynr[dlt][dq] = yn;
      ynf[dt * YNS + 16 * dq + l15] = yn;       // sxg-overlay region
    }
  }
  __syncthreads();                              // B3: sx2 reads done

  // ---- write ynb bf16 A-frags (sx2 overlay) ----
  #pragma unroll
  for (int dlt = 0; dlt < 2; ++dlt)
    #pragma unroll
    for (int dq = 0; dq < 4; ++dq)
      ynb[(dtbase + dlt) * YNBS + 16 * dq + l15] = f2bf(ynr[dlt][dq]);
  __syncthreads();                              // B4

  // ---- phase 4: z = yn@ck + cb via MFMA, PReLU, out = yn + z ----
  const float sl = prelu_slope[0];
  const int   o  = 16 * w + l15;                // wave w owns o-tile w
  const float cb = conv_bias[o];
  short8 bf0 = *(const short8*)&ckfrag[((w * 2 + 0) * 64 + lane) * 8];
  short8 bf1 = *(const short8*)&ckfrag[((w * 2 + 1) * 64 + lane) * 8];
  #pragma unroll
  for (int mt = 0; mt < 2; ++mt) {
    short8 af0 = *(const short8*)&ynb[(mt * 16 + l15) * YNBS + q * 8];
    short8 af1 = *(const short8*)&ynb[(mt * 16 + l15) * YNBS + 32 + q * 8];
    float4v zc = __builtin_amdgcn_mfma_f32_16x16x32_bf16(af0, bf0, zacc, 0, 0, 0);
    zc = __builtin_amdgcn_mfma_f32_16x16x32_bf16(af1, bf1, zc, 0, 0, 0);
    #pragma unroll
    for (int r = 0; r < 4; ++r) {
      int t  = mt * 16 + 4 * q + r;
      int tg = t0 + t;
      if (tg < TOUT) {
        float z = zc[r] + cb;
        z = (z >= 0.f) ? z : sl * z;
        out[((size_t)b * TOUT + tg) * CC + o] = ynf[t * YNS + o] + z;
      }
    }
  }
}

extern "C" void kernel_launch(void* const* d_in, const int* in_sizes, int n_in,
                              void* d_out, int out_size, void* d_ws, size_t ws_size,
                              hipStream_t stream)
{
  const float* x        = (const float*)d_in[0];
  const float* weights  = (const float*)d_in[1];
  const float* ln_scale = (const float*)d_in[2];
  const float* ln_bias  = (const float*)d_in[3];
  const float* ck       = (const float*)d_in[4];
  const float* cb       = (const float*)d_in[5];
  const float* slope    = (const float*)d_in[6];
  unsigned short* wfrag  = (unsigned short*)d_ws;                  // 57344 B
  unsigned short* ckfrag = (unsigned short*)((char*)d_ws + 57344); // 8192 B

  prep_frags<<<64, 256, 0, stream>>>(weights, ck, wfrag, ckfrag);
  convblock_main<<<BB * 256, 256, 0, stream>>>(x, wfrag, ckfrag, ln_scale,
                                               ln_bias, cb, slope, (float*)d_out);
}

// Round 14
// 110.442 us; speedup vs baseline: 2.2063x; 1.0049x over previous
//
#include <hip/hip_runtime.h>
#include <stdint.h>

#define BB 8
#define LLEN 16384
#define CC 64
#define TOUT 8186
#define TILE_T 32
#define NROWS 76            // 2*TILE_T + 12 halo rows
#define SXS 68              // fp32 words/row (272B)
#define SXGS 72             // shorts/row (144B)
#define YNS 66              // fp32 words/row
#define YNBS 76             // shorts/row

typedef __attribute__((ext_vector_type(8))) short short8;
typedef __attribute__((ext_vector_type(4))) float float4v;
typedef __attribute__((ext_vector_type(4))) unsigned short ushort4v;

__device__ inline unsigned short f2bf(float f) {
  union { float f; uint32_t u; } v; v.f = f;
  uint32_t r = v.u + 0x7fffu + ((v.u >> 16) & 1u);
  return (unsigned short)(r >> 16);
}
__device__ inline float rcp_fast(float x) {
  float r; asm("v_rcp_f32 %0, %1" : "=v"(r) : "v"(x)); return r;
}
__device__ inline float exp2_fast(float x) {
  float r; asm("v_exp_f32 %0, %1" : "=v"(r) : "v"(x)); return r;
}
// exp-form tanh (R6/R12-validated, absmax 0.03125): 5 inst/gate
// (mul, v_exp, add, v_rcp, fma); saturates exactly at +/-1.
__device__ inline float tanh_fast(float a) {
  float e = exp2_fast(a * 2.885390082f);        // e^{2a} = 2^{2a*log2(e)}
  return __builtin_fmaf(-2.0f, rcp_fast(e + 1.0f), 1.0f);
}

// Pack fp32 weights (C,C,K) -> bf16 MFMA B-frags (n = kk*64+d, d = 16*dq+l15),
// and fp32 conv_kernel (C,C) -> bf16 B-frags (n = o, k = c).
// NOTE (R13): remapping d -> 4*l15+dq (for contiguous sx2 reads) failed
// correctness (absmax 0.39) — root cause not found; keep this verified layout.
__global__ void prep_frags(const float* __restrict__ weights,
                           const float* __restrict__ ck,
                           unsigned short* __restrict__ wfrag,
                           unsigned short* __restrict__ ckfrag)
{
  int bid = blockIdx.x, tid = threadIdx.x;
  if (bid < 56) {                       // 28 ntiles x 2 khalves
    int nt = bid >> 1, kh = bid & 1;
    for (int e = tid; e < 512; e += 256) {
      int ln = e >> 3, j = e & 7;
      int kk = nt >> 2;                 // nt = kk*4 + dq
      int d  = (nt & 3) * 16 + (ln & 15);
      int cp = kh * 32 + (ln >> 4) * 8 + j;
      wfrag[(bid * 64 + ln) * 8 + j] = f2bf(weights[d * 448 + cp * 7 + kk]);
    }
  } else {                              // conv kernel: 4 ntiles x 2 khalves
    int bb2 = bid - 56;
    int nt = bb2 >> 1, kh = bb2 & 1;
    for (int e = tid; e < 512; e += 256) {
      int ln = e >> 3, j = e & 7;
      int oo = nt * 16 + (ln & 15);
      int c2 = kh * 32 + (ln >> 4) * 8 + j;
      ckfrag[(bb2 * 64 + ln) * 8 + j] = f2bf(ck[c2 * 64 + oo]);
    }
  }
}

// R12 (verified best): rolled kk-loop, exp tanh, swizzled sx2, VGPR~64.
__global__ __launch_bounds__(256, 4)
void convblock_main(const float* __restrict__ x,
                    const unsigned short* __restrict__ wfrag,
                    const unsigned short* __restrict__ ckfrag,
                    const float* __restrict__ ln_scale,
                    const float* __restrict__ ln_bias,
                    const float* __restrict__ conv_bias,
                    const float* __restrict__ prelu_slope,
                    float* __restrict__ out)
{
  __shared__ __align__(16) char smem[29888];
  float*          sx2 = (float*)smem;                    // [0, 20672)
  unsigned short* ynb = (unsigned short*)smem;           // overlay after B3 (4864 B)
  unsigned short* sxg = (unsigned short*)(smem + 20672); // 9216 B
  float*          ynf = (float*)(smem + 20672);          // overlay after B2 (8448 B)

  const int tid  = threadIdx.x;
  const int b    = blockIdx.x >> 8;
  const int t0   = (blockIdx.x & 255) * TILE_T;
  const int lane = tid & 63;
  const int w    = tid >> 6;
  const int l15  = tid & 15;
  const int q    = (tid >> 4) & 3;

  // ---- phase 1: stage x slab rows 2t0..2t0+75, float4 loads ----
  {
    const float* xb = x + (size_t)b * ((size_t)LLEN * CC);
    #pragma unroll
    for (int i = 0; i < 5; ++i) {
      int idx = tid + i * 256;                  // [0, 1216) float4s
      if (idx < NROWS * 16) {
        int row = idx >> 4, f4 = idx & 15, c0 = f4 * 4;
        int rowg = 2 * t0 + row;
        if (rowg > LLEN - 1) rowg = LLEN - 1;   // only feeds t >= TOUT (never stored)
        float4v v = *(const float4v*)(xb + (size_t)rowg * CC + c0);
        int base = row * SXS + 16 * (f4 & 3) + (f4 >> 2);  // swizzle (c&15)*4+(c>>4)
        sx2[base + 0]  = v[0];
        sx2[base + 4]  = v[1];
        sx2[base + 8]  = v[2];
        sx2[base + 12] = v[3];
        if (row >= 12) {
          ushort4v p;
          p[0] = f2bf(v[0]); p[1] = f2bf(v[1]); p[2] = f2bf(v[2]); p[3] = f2bf(v[3]);
          *(ushort4v*)&sxg[(row - 12) * SXGS + c0] = p;
        }
      }
    }
  }
  float lnS[4], lnB[4];
  #pragma unroll
  for (int dq = 0; dq < 4; ++dq) {
    lnS[dq] = ln_scale[16 * dq + l15];
    lnB[dq] = ln_bias[16 * dq + l15];
  }
  __syncthreads();                              // B1

  short8 a0 = *(const short8*)&sxg[(16 * w + l15) * SXGS + q * 8];
  short8 a1 = *(const short8*)&sxg[(16 * w + l15) * SXGS + 32 + q * 8];
  __syncthreads();                              // B2: sxg dead, ynf may overlay

  // ---- phase 2+3 fused: ROLLED per-kk loop: MFMA -> tanh -> y ----
  float y[2][4];
  #pragma unroll
  for (int dlt = 0; dlt < 2; ++dlt)
    #pragma unroll
    for (int dq = 0; dq < 4; ++dq) y[dlt][dq] = 0.f;

  const float4v zacc = (float4v){0.f, 0.f, 0.f, 0.f};
  const int dtbase = 8 * w + 2 * q;             // local t = dtbase + dlt
  const unsigned short* wp = wfrag + lane * 8;  // += 4096 shorts per kk
  #pragma unroll 1
  for (int kk = 0; kk < 7; ++kk) {
    float4v acc[4];
    #pragma unroll
    for (int dq = 0; dq < 4; ++dq) {
      short8 b0 = *(const short8*)(wp + dq * 1024);
      short8 b1 = *(const short8*)(wp + dq * 1024 + 512);
      float4v a = __builtin_amdgcn_mfma_f32_16x16x32_bf16(a0, b0, zacc, 0, 0, 0);
      acc[dq] = __builtin_amdgcn_mfma_f32_16x16x32_bf16(a1, b1, a, 0, 0, 0);
    }
    #pragma unroll
    for (int dlt = 0; dlt < 2; ++dlt) {
      int rowe = 2 * (dtbase + dlt) + 2 * kk;
      float4v xe = *(const float4v*)&sx2[rowe * SXS + l15 * 4];
      float4v xo = *(const float4v*)&sx2[(rowe + 1) * SXS + l15 * 4];
      #pragma unroll
      for (int dq = 0; dq < 4; ++dq) {
        float ge = tanh_fast(acc[dq][2 * dlt + 0]);
        float go = tanh_fast(acc[dq][2 * dlt + 1]);
        y[dlt][dq] += xe[dq] * ge + xo[dq] * go;
      }
    }
    wp += 4096;
  }
  // residual x[12+2t] (even element of the kk=6 row)
  #pragma unroll
  for (int dlt = 0; dlt < 2; ++dlt) {
    int rowe = 2 * (dtbase + dlt) + 12;
    float4v xe = *(const float4v*)&sx2[rowe * SXS + l15 * 4];
    #pragma unroll
    for (int dq = 0; dq < 4; ++dq) y[dlt][dq] += xe[dq];
  }

  // ---- LayerNorm (registers + 16-lane shuffle) ----
  float ynr[2][4];
  #pragma unroll
  for (int dlt = 0; dlt < 2; ++dlt) {
    float s1 = y[dlt][0] + y[dlt][1] + y[dlt][2] + y[dlt][3];
    float s2 = y[dlt][0]*y[dlt][0] + y[dlt][1]*y[dlt][1]
             + y[dlt][2]*y[dlt][2] + y[dlt][3]*y[dlt][3];
    #pragma unroll
    for (int m = 1; m < 16; m <<= 1) {
      s1 += __shfl_xor(s1, m, 64);
      s2 += __shfl_xor(s2, m, 64);
    }
    float mu   = s1 * (1.0f / 64.0f);
    float var  = s2 * (1.0f / 64.0f) - mu * mu;
    float rstd = rsqrtf(var + 1e-6f);
    int dt = dtbase + dlt;
    #pragma unroll
    for (int dq = 0; dq < 4; ++dq) {
      float yn = (y[dlt][dq] - mu) * rstd * lnS[dq] + lnB[dq];
      ynr[dlt][dq] = yn;
      ynf[dt * YNS + 16 * dq + l15] = yn;       // sxg-overlay region
    }
  }
  __syncthreads();                              // B3: sx2 reads done

  // ---- write ynb bf16 A-frags (sx2 overlay) ----
  #pragma unroll
  for (int dlt = 0; dlt < 2; ++dlt)
    #pragma unroll
    for (int dq = 0; dq < 4; ++dq)
      ynb[(dtbase + dlt) * YNBS + 16 * dq + l15] = f2bf(ynr[dlt][dq]);
  __syncthreads();                              // B4

  // ---- phase 4: z = yn@ck + cb via MFMA, PReLU, out = yn + z ----
  const float sl = prelu_slope[0];
  const int   o  = 16 * w + l15;                // wave w owns o-tile w
  const float cb = conv_bias[o];
  short8 bf0 = *(const short8*)&ckfrag[((w * 2 + 0) * 64 + lane) * 8];
  short8 bf1 = *(const short8*)&ckfrag[((w * 2 + 1) * 64 + lane) * 8];
  #pragma unroll
  for (int mt = 0; mt < 2; ++mt) {
    short8 af0 = *(const short8*)&ynb[(mt * 16 + l15) * YNBS + q * 8];
    short8 af1 = *(const short8*)&ynb[(mt * 16 + l15) * YNBS + 32 + q * 8];
    float4v zc = __builtin_amdgcn_mfma_f32_16x16x32_bf16(af0, bf0, zacc, 0, 0, 0);
    zc = __builtin_amdgcn_mfma_f32_16x16x32_bf16(af1, bf1, zc, 0, 0, 0);
    #pragma unroll
    for (int r = 0; r < 4; ++r) {
      int t  = mt * 16 + 4 * q + r;
      int tg = t0 + t;
      if (tg < TOUT) {
        float z = zc[r] + cb;
        z = (z >= 0.f) ? z : sl * z;
        out[((size_t)b * TOUT + tg) * CC + o] = ynf[t * YNS + o] + z;
      }
    }
  }
}

extern "C" void kernel_launch(void* const* d_in, const int* in_sizes, int n_in,
                              void* d_out, int out_size, void* d_ws, size_t ws_size,
                              hipStream_t stream)
{
  const float* x        = (const float*)d_in[0];
  const float* weights  = (const float*)d_in[1];
  const float* ln_scale = (const float*)d_in[2];
  const float* ln_bias  = (const float*)d_in[3];
  const float* ck       = (const float*)d_in[4];
  const float* cb       = (const float*)d_in[5];
  const float* slope    = (const float*)d_in[6];
  unsigned short* wfrag  = (unsigned short*)d_ws;                  // 57344 B
  unsigned short* ckfrag = (unsigned short*)((char*)d_ws + 57344); // 8192 B

  prep_frags<<<64, 256, 0, stream>>>(weights, ck, wfrag, ckfrag);
  convblock_main<<<BB * 256, 256, 0, stream>>>(x, wfrag, ckfrag, ln_scale,
                                               ln_bias, cb, slope, (float*)d_out);
}